// Round 10
// baseline (182.243 us; speedup 1.0000x reference)
//
#include <hip/hip_runtime.h>
#include <stdint.h>

// GCN: out[u] = (sum_{(u,v) in E} x[v]) @ W + bias, E sorted by u.
// R9 model closure: gather is bound by lines-in-flight x latency
// (~64 MSHR/CU x ~700cyc L3 => ~45us for 2.56M lines). R10 attacks LATENCY:
// feature-sliced gather (4 slices x 32 feats = 1 line/edge/slice; slice
// footprint 3.2MB fits a 4MiB per-XCD L2), slices pinned to XCDs via the
// blockIdx%8 round-robin heuristic. Gather writes bf16 agg to ws; a separate
// small MFMA GEMM kernel computes out = agg @ W + bias. Prep (CSR scatter +
// W^T + x->bf16 cast) merged into one kernel. Loads stay unconditional with
// scale-by-0 (R8: conditional loads serialize).

typedef __attribute__((ext_vector_type(8))) short bf16x8;   // 8 bf16 = 4 VGPRs
typedef __attribute__((ext_vector_type(4))) float f32x4;    // MFMA C/D

__device__ __forceinline__ unsigned short f2bf(float f) {
    union { float f; uint32_t u; } c; c.f = f;
    uint32_t u = c.u;
    uint32_t r = (u + 0x7FFFu + ((u >> 16) & 1u)) >> 16;  // RNE
    return (unsigned short)r;
}
__device__ __forceinline__ float bf2f(unsigned short u) {
    union { uint32_t u; float f; } c; c.u = ((uint32_t)u) << 16;
    return c.f;
}

// ---- prep: CSR row_ptr (scatter + parallel tail), W^T bf16, x -> bf16 ----
__global__ __launch_bounds__(256)
void gcn_prep(const float* __restrict__ x, const int* __restrict__ eu,
              const float* __restrict__ W,
              int* __restrict__ row_ptr, unsigned short* __restrict__ Wg,
              unsigned short* __restrict__ xb, int N, int E, int n8)
{
    const int g = blockIdx.x * 256 + threadIdx.x;
    if (g < n8) {                      // cast 8 floats -> 8 bf16 (16B store)
        const float4* x4 = (const float4*)x;
        float4 a = x4[2 * g], b = x4[2 * g + 1];
        union { unsigned short u[8]; uint4 v; } pk;
        pk.u[0] = f2bf(a.x); pk.u[1] = f2bf(a.y); pk.u[2] = f2bf(a.z); pk.u[3] = f2bf(a.w);
        pk.u[4] = f2bf(b.x); pk.u[5] = f2bf(b.y); pk.u[6] = f2bf(b.z); pk.u[7] = f2bf(b.w);
        ((uint4*)xb)[g] = pk.v;
    }
    if (g < E) {                       // interior transitions (bounded gaps)
        int cur  = eu[g];
        int prev = (g > 0) ? eu[g - 1] : -1;
        for (int r = prev + 1; r <= cur; ++r) row_ptr[r] = g;
    }
    if (g <= N) {                      // parallel tail fill (R6 bug fix)
        int last = eu[E - 1];
        if (g > last) row_ptr[g] = E;
    }
    if (g < 16384) {                   // W^T bf16: Wg[n*128+k] = bf16(W[k][n])
        int k = g >> 7, n = g & 127;
        Wg[n * 128 + k] = f2bf(W[g]);
    }
}

// ---- gather: slice s of 32 feats; 16 edges/instr (4 lanes x 16B per edge);
//      2 loads (32 edges) in flight per volley; 8 rows/wave interleaved ----
__global__ __launch_bounds__(256)
void gcn_gather(const unsigned short* __restrict__ xb,  // bf16 x [N][128]
                const int* __restrict__ ev,
                const int* __restrict__ row_ptr,        // [N+1]
                unsigned short* __restrict__ agg,       // bf16 [N][128]
                int N, int E, int TWS)                  // waves per slice
{
    const int t    = threadIdx.x;
    const int wid  = t >> 6;
    const int lane = t & 63;
    const int slot = lane >> 2;        // 0..15: edge slot
    const int fl   = lane & 3;         // 16B chunk within the 64B slice

    const int bid   = blockIdx.x;
    const int slice = (bid & 7) >> 1;              // XCD-pinned (blockIdx%8 heuristic)
    const int sidx  = ((bid >> 3) << 1) + (bid & 1);
    const int wgs   = sidx * 4 + wid;              // wave id within slice
    const int fo    = slice * 32 + fl * 8;         // ushort offset in a row

    // Row bounds: lane 2m -> rp[r_m], lane 2m+1 -> rp[r_m + 1]
    int bnd;
    {
        const int m = (lane >> 1) & 7, e = lane & 1;
        bnd = row_ptr[min(wgs + m * TWS + e, N)];
    }

    // prefetch row 0's first 64 edge indices
    int vIdx = ev[min(__shfl(bnd, 0) + lane, E - 1)];

    for (int m = 0; m < 8; ++m) {
        const int s = __shfl(bnd, 2 * m);
        const int c = __shfl(bnd, 2 * m + 1) - s;
        int vNext = (m < 7) ? ev[min(__shfl(bnd, 2 * m + 2) + lane, E - 1)] : 0;

        float fa[8];
        #pragma unroll
        for (int i = 0; i < 8; ++i) fa[i] = 0.f;

        for (int base = 0; base < c; base += 32) {     // 32 edges per volley
            if (base && ((base & 63) == 0))
                vIdx = ev[min(s + base + lane, E - 1)];
            const int e0 = base + slot, e1 = base + 16 + slot;
            int v0 = __shfl(vIdx, e0 & 63);
            int v1 = __shfl(vIdx, e1 & 63);
            const float s0 = (e0 < c) ? 1.0f : 0.0f;
            const float s1 = (e1 < c) ? 1.0f : 0.0f;
            v0 = (e0 < c) ? v0 : 0;                    // dead -> row 0 (L1-hot)
            v1 = (e1 < c) ? v1 : 0;
            bf16x8 t0 = *(const bf16x8*)(xb + (size_t)v0 * 128 + fo);  // 1 line/edge
            bf16x8 t1 = *(const bf16x8*)(xb + (size_t)v1 * 128 + fo);
            #pragma unroll
            for (int i = 0; i < 8; ++i) fa[i] = fmaf(bf2f((unsigned short)t0[i]), s0, fa[i]);
            #pragma unroll
            for (int i = 0; i < 8; ++i) fa[i] = fmaf(bf2f((unsigned short)t1[i]), s1, fa[i]);
        }
        vIdx = vNext;

        // reduce across the 16 slots (xor tree over lanes 4,8,16,32)
        #pragma unroll
        for (int i = 0; i < 8; ++i) {
            fa[i] += __shfl_xor(fa[i], 4);
            fa[i] += __shfl_xor(fa[i], 8);
            fa[i] += __shfl_xor(fa[i], 16);
            fa[i] += __shfl_xor(fa[i], 32);
        }
        if (slot == 0) {                               // lanes 0..3: 64B store
            const int row = wgs + m * TWS;
            if (row < N) {
                union { unsigned short u[8]; uint4 v; } pk;
                #pragma unroll
                for (int i = 0; i < 8; ++i) pk.u[i] = f2bf(fa[i]);
                *(uint4*)(agg + (size_t)row * 128 + fo) = pk.v;
            }
        }
    }
}

// ---- GEMM: out[N][128] = agg(bf16) @ W + bias, 64 rows/block, no LDS ----
__global__ __launch_bounds__(256)
void gcn_gemm(const unsigned short* __restrict__ agg,
              const unsigned short* __restrict__ Wg,   // bf16 W^T [n][k]
              const float* __restrict__ bias,
              float* __restrict__ out, int N)
{
    const int t    = threadIdx.x;
    const int wid  = t >> 6;
    const int lane = t & 63;
    const int quad = lane >> 4;
    const int l15  = lane & 15;
    const int r0   = blockIdx.x * 64 + wid * 16;

    f32x4 acc[8];
    #pragma unroll
    for (int nt = 0; nt < 8; ++nt) { acc[nt].x = 0.f; acc[nt].y = 0.f; acc[nt].z = 0.f; acc[nt].w = 0.f; }

    const int ar = min(r0 + l15, N - 1);   // tail-safe A row (stores guarded)
    #pragma unroll
    for (int ks = 0; ks < 4; ++ks) {
        const int kofs = ks * 32 + quad * 8;
        bf16x8 a = *(const bf16x8*)(agg + (size_t)ar * 128 + kofs);   // A[m=l15][k..]
        #pragma unroll
        for (int nt = 0; nt < 8; ++nt) {
            bf16x8 b = *(const bf16x8*)(Wg + (nt * 16 + l15) * 128 + kofs); // B^T[n][k]
            acc[nt] = __builtin_amdgcn_mfma_f32_16x16x32_bf16(a, b, acc[nt], 0, 0, 0);
        }
    }

    // C/D: col = lane&15, row = quad*4 + reg
    #pragma unroll
    for (int nt = 0; nt < 8; ++nt) {
        const int col = nt * 16 + l15;
        const float bcol = bias[col];
        #pragma unroll
        for (int r = 0; r < 4; ++r) {
            const int row = r0 + quad * 4 + r;
            if (row < N)
                __builtin_nontemporal_store(acc[nt][r] + bcol,
                                            &out[(long long)row * 128 + col]);
        }
    }
}

extern "C" void kernel_launch(void* const* d_in, const int* in_sizes, int n_in,
                              void* d_out, int out_size, void* d_ws, size_t ws_size,
                              hipStream_t stream) {
    const float* x    = (const float*)d_in[0];
    const int*   ei   = (const int*)d_in[1];     // int32 on device
    const float* W    = (const float*)d_in[2];
    const float* bias = (const float*)d_in[3];
    float*       out  = (float*)d_out;

    const int N = in_sizes[0] / 128;
    const int E = in_sizes[1] / 2;

    const size_t rp_b    = ((size_t)(N + 1) * 4 + 255) & ~(size_t)255;
    const size_t wg_off  = rp_b;
    const size_t xb_off  = (wg_off + 32768 + 255) & ~(size_t)255;
    const size_t xb_b    = (size_t)N * 128 * 2;
    const size_t agg_off = (xb_off + xb_b + 255) & ~(size_t)255;

    int*            row_ptr = (int*)d_ws;
    unsigned short* Wg      = (unsigned short*)((char*)d_ws + wg_off);
    unsigned short* xb      = (unsigned short*)((char*)d_ws + xb_off);
    unsigned short* agg     = (unsigned short*)((char*)d_ws + agg_off);
    // ws evidence: harness poisons 256 MiB each iter; we need ~26 MB.

    const int n8 = N * 16;
    const int prep_threads = (n8 > E ? n8 : E) > N + 1 ? (n8 > E ? n8 : E) : N + 1;
    gcn_prep<<<(prep_threads + 255) / 256, 256, 0, stream>>>(x, ei, W, row_ptr, Wg, xb, N, E, n8);

    // gather: 4 slices, 8 rows/wave. blocks/slice even so grid = 8 * B2.
    const int waves_per_slice = (N + 7) / 8;                   // 6250
    const int blk_per_slice   = (waves_per_slice + 3) / 4;     // 1563
    const int B2              = (blk_per_slice + 1) / 2;       // 782
    const int TWS             = B2 * 2 * 4;                    // 6256 waves/slice
    gcn_gather<<<B2 * 8, 256, 0, stream>>>(xb, ei + E, row_ptr, agg, N, E, TWS);

    gcn_gemm<<<(N + 63) / 64, 256, 0, stream>>>(agg, Wg, bias, out, N);
}

// Round 12
// 112.131 us; speedup vs baseline: 1.6253x; 1.6253x over previous
//
#include <hip/hip_runtime.h>
#include <stdint.h>

// GCN: out[u] = (sum_{(u,v) in E} x[v]) @ W + bias, E sorted by u.
// R10 lesson: per-wave loads-in-flight is THE lever (slicing cut MLP 4x and
// doubled time despite better L2 hit + 3x occupancy). R11 = R9 fused
// structure + 2-row software pipeline (16 gathers outstanding/wave), all
// row-index loads issued upfront, contiguous rows + bias-only fast path for
// the empty half of the graph (u only spans ~N/2 for this edge construction).
// R11b: fix — __builtin_nontemporal_store needs a native vector type, not
// HIP_vector_type<float,4>; use ext_vector f32x4 for the fast-path store.

typedef __attribute__((ext_vector_type(8))) short bf16x8;   // 8 bf16 = 4 VGPRs
typedef __attribute__((ext_vector_type(4))) float f32x4;    // MFMA C/D, NT stores

#define WSTRIDE 136   // A-tile k-stride (bf16); row pitch 272B = 17*16B (aligned)

__device__ __forceinline__ unsigned short f2bf(float f) {
    union { float f; uint32_t u; } c; c.f = f;
    uint32_t u = c.u;
    uint32_t r = (u + 0x7FFFu + ((u >> 16) & 1u)) >> 16;  // RNE
    return (unsigned short)r;
}
__device__ __forceinline__ float bf2f(unsigned short u) {
    union { uint32_t u; float f; } c; c.u = ((uint32_t)u) << 16;
    return c.f;
}

// ---- prep: CSR row_ptr (scatter + parallel tail), W^T bf16, x -> bf16 ----
__global__ __launch_bounds__(256)
void gcn_prep(const float* __restrict__ x, const int* __restrict__ eu,
              const float* __restrict__ W,
              int* __restrict__ row_ptr, unsigned short* __restrict__ Wg,
              unsigned short* __restrict__ xb, int N, int E, int n8)
{
    const int g = blockIdx.x * 256 + threadIdx.x;
    if (g < n8) {                      // cast 8 floats -> 8 bf16 (16B store)
        const float4* x4 = (const float4*)x;
        float4 a = x4[2 * g], b = x4[2 * g + 1];
        union { unsigned short u[8]; uint4 v; } pk;
        pk.u[0] = f2bf(a.x); pk.u[1] = f2bf(a.y); pk.u[2] = f2bf(a.z); pk.u[3] = f2bf(a.w);
        pk.u[4] = f2bf(b.x); pk.u[5] = f2bf(b.y); pk.u[6] = f2bf(b.z); pk.u[7] = f2bf(b.w);
        ((uint4*)xb)[g] = pk.v;
    }
    if (g < E) {                       // interior transitions (bounded gaps)
        int cur  = eu[g];
        int prev = (g > 0) ? eu[g - 1] : -1;
        for (int r = prev + 1; r <= cur; ++r) row_ptr[r] = g;
    }
    if (g <= N) {                      // parallel tail fill (R6 bug fix)
        int last = eu[E - 1];
        if (g > last) row_ptr[g] = E;
    }
    if (g < 16384) {                   // W^T bf16: Wg[n*128+k] = bf16(W[k][n])
        int k = g >> 7, n = g & 127;
        Wg[n * 128 + k] = f2bf(W[g]);
    }
}

__global__ __launch_bounds__(256)
void gcn_main(const unsigned short* __restrict__ xb,   // bf16 x [N][128]
              const int* __restrict__ ev,
              const int* __restrict__ row_ptr,         // [N+1]
              const unsigned short* __restrict__ Wg,   // bf16 W^T [128][128]
              const float* __restrict__ bias,
              float* __restrict__ out,                 // [N][128] f32
              int N, int E)
{
    __shared__ __align__(16) unsigned short At[16 * WSTRIDE];  // block tile [mi][k]

    const int t     = threadIdx.x;
    const int wid   = t >> 6;
    const int lane  = t & 63;
    const int quad  = lane >> 4;
    const int l15   = lane & 15;
    const int eslot = lane >> 4;       // 0..3: edge slot within a gather instr
    const int fo    = l15 * 8;         // 16B chunk of the 256B bf16 row

    const int r0 = blockIdx.x * 16;    // contiguous 16 rows per block

    // ---- 17 boundaries, one coalesced load ----
    int bnd = row_ptr[min(r0 + (lane < 17 ? lane : 16), N)];

    // ---- bias-only fast path (block-uniform) ----
    if (__shfl(bnd, 0) == __shfl(bnd, 16)) {
        const f32x4* b4 = (const f32x4*)bias;
        f32x4*       o4 = (f32x4*)out;
        #pragma unroll
        for (int i = 0; i < 2; ++i) {
            const int f   = i * 256 + t;           // 0..511
            const int row = r0 + (f >> 5);
            if (row < N)
                __builtin_nontemporal_store(b4[f & 31], &o4[(size_t)row * 32 + (f & 31)]);
        }
        return;
    }

    // ---- per-wave: 4 rows, 2-row software-pipelined gather ----
    int sA[4], cA[4], vI[4];
    #pragma unroll
    for (int m = 0; m < 4; ++m) {
        sA[m] = __shfl(bnd, wid * 4 + m);
        cA[m] = __shfl(bnd, wid * 4 + m + 1) - sA[m];
    }
    #pragma unroll
    for (int m = 0; m < 4; ++m)        // ALL index loads upfront (4 coalesced)
        vI[m] = ev[min(sA[m] + lane, E - 1)];

    bf16x8 tv[2][8];                   // two volley buffers (32 edges each)

    // issue volley 0 of row 0
    if (cA[0] > 0) {
        #pragma unroll
        for (int k = 0; k < 8; ++k) {
            const int v = __shfl(vI[0], k * 4 + eslot);
            tv[0][k] = *(const bf16x8*)(xb + (size_t)v * 128 + fo);
        }
    }

    #pragma unroll
    for (int m = 0; m < 4; ++m) {
        const int buf = m & 1;
        // issue next row's volley BEFORE consuming this row's (16 in flight)
        if (m < 3 && cA[m + 1] > 0) {
            #pragma unroll
            for (int k = 0; k < 8; ++k) {
                const int v = __shfl(vI[m + 1], k * 4 + eslot);
                tv[(m + 1) & 1][k] = *(const bf16x8*)(xb + (size_t)v * 128 + fo);
            }
        }

        float fa[8];
        #pragma unroll
        for (int i = 0; i < 8; ++i) fa[i] = 0.f;

        if (cA[m] > 0) {
            #pragma unroll
            for (int k = 0; k < 8; ++k) {              // waits only on tv[buf]
                const float s = (k * 4 + eslot < cA[m]) ? 1.0f : 0.0f;
                #pragma unroll
                for (int i = 0; i < 8; ++i)
                    fa[i] = fmaf(bf2f((unsigned short)tv[buf][k][i]), s, fa[i]);
            }
            // rare tail (deg > 32); serial, reuses this row's buffer
            for (int base = 32; base < cA[m]; base += 32) {
                if ((base & 63) == 0)
                    vI[m] = ev[min(sA[m] + base + lane, E - 1)];
                #pragma unroll
                for (int k = 0; k < 8; ++k) {
                    const int v = __shfl(vI[m], (base + k * 4 + eslot) & 63);
                    tv[buf][k] = *(const bf16x8*)(xb + (size_t)v * 128 + fo);
                }
                #pragma unroll
                for (int k = 0; k < 8; ++k) {
                    const float s = (base + k * 4 + eslot < cA[m]) ? 1.0f : 0.0f;
                    #pragma unroll
                    for (int i = 0; i < 8; ++i)
                        fa[i] = fmaf(bf2f((unsigned short)tv[buf][k][i]), s, fa[i]);
                }
            }
        }

        // reduce the 4 edge slots (lanes l15, +16, +32, +48)
        #pragma unroll
        for (int i = 0; i < 8; ++i) {
            fa[i] += __shfl_xor(fa[i], 16);
            fa[i] += __shfl_xor(fa[i], 32);
        }
        if (eslot == 0) {              // lanes 0..15: one 16B store covers the row
            union { unsigned short u[8]; uint4 v; } pk;
            #pragma unroll
            for (int i = 0; i < 8; ++i) pk.u[i] = f2bf(fa[i]);
            *(uint4*)(At + (wid * 4 + m) * WSTRIDE + fo) = pk.v;
        }
    }
    __syncthreads();   // block shares the 16-row tile

    // ---- MFMA: 16 rows x 32 cols per wave ----
    f32x4 acc[2];
    #pragma unroll
    for (int nt = 0; nt < 2; ++nt) { acc[nt].x = 0.f; acc[nt].y = 0.f; acc[nt].z = 0.f; acc[nt].w = 0.f; }

    #pragma unroll
    for (int ks = 0; ks < 4; ++ks) {
        const int kofs = ks * 32 + quad * 8;
        bf16x8 a = *(const bf16x8*)(At + l15 * WSTRIDE + kofs);   // A[mi=l15][k..]
        #pragma unroll
        for (int nt = 0; nt < 2; ++nt) {
            const int col = wid * 32 + nt * 16 + l15;
            bf16x8 b = *(const bf16x8*)(Wg + col * 128 + kofs);   // B^T[n=col][k..]
            acc[nt] = __builtin_amdgcn_mfma_f32_16x16x32_bf16(a, b, acc[nt], 0, 0, 0);
        }
    }

    // ---- Epilogue. C/D: col = lane&15, local row mi = quad*4 + reg ----
    #pragma unroll
    for (int nt = 0; nt < 2; ++nt) {
        const int col = wid * 32 + nt * 16 + l15;
        const float bcol = bias[col];
        #pragma unroll
        for (int r = 0; r < 4; ++r) {
            const int row = r0 + quad * 4 + r;
            if (row < N)
                __builtin_nontemporal_store(acc[nt][r] + bcol,
                                            &out[(long long)row * 128 + col]);
        }
    }
}

extern "C" void kernel_launch(void* const* d_in, const int* in_sizes, int n_in,
                              void* d_out, int out_size, void* d_ws, size_t ws_size,
                              hipStream_t stream) {
    const float* x    = (const float*)d_in[0];
    const int*   ei   = (const int*)d_in[1];     // int32 on device
    const float* W    = (const float*)d_in[2];
    const float* bias = (const float*)d_in[3];
    float*       out  = (float*)d_out;

    const int N = in_sizes[0] / 128;
    const int E = in_sizes[1] / 2;

    const size_t rp_b   = ((size_t)(N + 1) * 4 + 255) & ~(size_t)255;
    const size_t wg_off = rp_b;
    const size_t xb_off = (wg_off + 32768 + 255) & ~(size_t)255;

    int*            row_ptr = (int*)d_ws;
    unsigned short* Wg      = (unsigned short*)((char*)d_ws + wg_off);
    unsigned short* xb      = (unsigned short*)((char*)d_ws + xb_off);

    const int n8 = N * 16;
    int prep_threads = n8 > E ? n8 : E;
    if (prep_threads < N + 1) prep_threads = N + 1;
    gcn_prep<<<(prep_threads + 255) / 256, 256, 0, stream>>>(x, ei, W, row_ptr, Wg, xb, N, E, n8);

    const int grid = (N + 15) / 16;   // contiguous 16 rows/block, 4 per wave
    gcn_main<<<grid, 256, 0, stream>>>(xb, ei + E, row_ptr, Wg, bias, out, N, E);
}